// Round 2
// baseline (1766.474 us; speedup 1.0000x reference)
//
#include <hip/hip_runtime.h>

// ---------------------------------------------------------------------------
// AttentionModule fused pipeline, MI355X (gfx950) — round 2.
// Pipelined streaming GEMMs (double-buffered LDS, 1 sync/tile, loads in
// flight during compute), channel-inner layout for f16 intermediates,
// softmax+final fused into the scores GEMM epilogue.
//
//  K0 prep    : zero stats, convert W_grp/W_fo to f16
//  K1 feat    : f1 = relu(W_feat@feat+b)  (B,64,N) fp32  + gn1 stats g0..15
//  K2 gemm    : x1h = relu(W_grp@gf+b)    [b][p][64] f16 + gn1 stats g16..31
//  K4 fold    : gn1 -> W1p[b] (f16), b1p[b]
//  K5 u       : u[b,n,co] = W1p_lo @ f1 + b1p   (B,N,128) fp32
//  K6 gemm    : x2 = relu(W1p_hi@x1h + u) [b][p][128] f16 + gn2 stats
//  K3 gemm    : y3 = W_fo@gfo+b (raw)     [b][co][p] f16  + gn3 stats
//  K7 folds   : gn2 -> W2p[b],b2p[b];  gn3 -> s3,t3
//  K8 gemm    : scores=W2p@x2+b2p -> mask -> softmax(K) (regs, fp32)
//               -> out[b,c,n] = sum_k relu(s3*y3+t3)*wgt   (fused final)
// ---------------------------------------------------------------------------

#define B_   4
#define N_   4096
#define KK_  32
#define NK_  131072   // N_*KK_
#define C_   128
#define EPSV 1e-5f

typedef _Float16 hf8 __attribute__((ext_vector_type(8)));
typedef _Float16 hf4 __attribute__((ext_vector_type(4)));
typedef float    f4  __attribute__((ext_vector_type(4)));

// ---------------------------------------------------------------------------
__global__ void prep_k(const float* __restrict__ Wgrp, const float* __restrict__ Wfo,
                       _Float16* __restrict__ Wgrp_h, _Float16* __restrict__ Wfo_h,
                       float* __restrict__ stats)
{
    int tid = blockIdx.x * 256 + threadIdx.x;
    if (tid < 64 * 128)  Wgrp_h[tid] = (_Float16)Wgrp[tid];
    if (tid < 128 * 128) Wfo_h[tid]  = (_Float16)Wfo[tid];
    if (tid < 768)       stats[tid]  = 0.0f;
}

// ---------------------------------------------------------------------------
// K1: f1 = relu(W_feat @ feat + b), fp32 (B,64,N); gn1 stats groups 0..15
__global__ void feat_k(const float* __restrict__ feat, const float* __restrict__ Wf,
                       const float* __restrict__ bfeat, float* __restrict__ f1r,
                       float* __restrict__ stats1)
{
    __shared__ float fs[128][64];
    __shared__ float gst[32];
    int tid = threadIdx.x, b = blockIdx.y, n0 = blockIdx.x * 64;
    if (tid < 32) gst[tid] = 0.0f;
    for (int i = tid; i < 128 * 64; i += 256) {
        int ci = i >> 6, n = i & 63;
        fs[ci][n] = feat[((size_t)b * 128 + ci) * N_ + n0 + n];
    }
    __syncthreads();
    int n = tid & 63, cb = (tid >> 6) * 16;
    float gs1[4] = {0,0,0,0}, gs2[4] = {0,0,0,0};
    for (int j = 0; j < 16; j++) {
        int c = cb + j;
        float a = bfeat[c];
        #pragma unroll 16
        for (int ci = 0; ci < 128; ci++) a += Wf[c * 128 + ci] * fs[ci][n];
        a = fmaxf(a, 0.0f);
        f1r[((size_t)b * 64 + c) * N_ + n0 + n] = a;
        gs1[j >> 2] += a; gs2[j >> 2] += a * a;
    }
    for (int g = 0; g < 4; g++) {
        atomicAdd(&gst[((cb >> 2) + g) * 2 + 0], gs1[g]);
        atomicAdd(&gst[((cb >> 2) + g) * 2 + 1], gs2[g]);
    }
    __syncthreads();
    if (tid < 32) atomicAdd(&stats1[b * 64 + tid], gst[tid]);
}

// ---------------------------------------------------------------------------
__global__ void fold_k(const float* __restrict__ stats, const float* __restrict__ gw,
                       const float* __restrict__ gb, const float* __restrict__ Wsrc,
                       const float* __restrict__ bsrc, _Float16* __restrict__ Wdst,
                       float* __restrict__ bdst, float* __restrict__ sdst,
                       float* __restrict__ tdst, int lowcnt)
{
    int b = blockIdx.x, tid = threadIdx.x;
    __shared__ float ss[128], st[128];
    if (tid < 128) {
        int c = tid, g = c >> 2;
        float d  = (lowcnt && g < 16) ? (4.0f * N_) : (4.0f * NK_);
        float S1 = stats[(b * 32 + g) * 2], S2 = stats[(b * 32 + g) * 2 + 1];
        float mu = S1 / d;
        float var = fmaxf(S2 / d - mu * mu, 0.0f);
        float s = gw[c] * rsqrtf(var + EPSV);
        float t = gb[c] - mu * s;
        ss[c] = s; st[c] = t;
        if (sdst) { sdst[b * 128 + c] = s; tdst[b * 128 + c] = t; }
    }
    __syncthreads();
    if (Wdst && tid < 128) {
        int co = tid;
        float a = bsrc[co];
        for (int c = 0; c < 128; c++) {
            float w = Wsrc[co * 128 + c];
            a += w * st[c];
            Wdst[((size_t)b * 128 + co) * 128 + c] = (_Float16)(w * ss[c]);
        }
        bdst[b * 128 + co] = a;
    }
}

// ---------------------------------------------------------------------------
// K5: u[b][n][co] = b1p[co] + sum_{c<64} W1p[b][co][c] * f1[b][c][n]   (fp32)
__global__ void upass_k(const float* __restrict__ f1r, const _Float16* __restrict__ W1p,
                        const float* __restrict__ b1p, float* __restrict__ u)
{
    int b = blockIdx.y, n0 = blockIdx.x * 32, tid = threadIdx.x;
    __shared__ float fs[64][33];
    __shared__ _Float16 wl[128][68];
    for (int i = tid; i < 64 * 32; i += 256) {
        int c = i >> 5, n = i & 31;
        fs[c][n] = f1r[((size_t)b * 64 + c) * N_ + n0 + n];
    }
    for (int i = tid; i < 128 * 64; i += 256) {
        int co = i >> 6, c = i & 63;
        wl[co][c] = W1p[((size_t)b * 128 + co) * 128 + c];
    }
    __syncthreads();
    int co = tid & 127, nh = tid >> 7;
    float bb = b1p[b * 128 + co];
    for (int ps = 0; ps < 16; ps++) {
        int n = nh * 16 + ps;
        float a = bb;
        #pragma unroll 16
        for (int c = 0; c < 64; c++) a += (float)wl[co][c] * fs[c][n];
        u[((size_t)b * N_ + n0 + n) * C_ + co] = a;
    }
}

// ---------------------------------------------------------------------------
// Pipelined streaming GEMM: OUT[co][p] = sum_c W[co][c]*X[c][p] over 64-pos
// tiles, double-buffered LDS, one __syncthreads per tile, next tile's global
// loads issued right after the barrier (in flight through compute+epilogue).
// MFMA D(m=p, n=co). A-frags from LDS xs[p][c] (pad+4, all-8B DS ops).
// SRCF32: src is fp32 [b][c][p] (in-register 4x4 transpose to LDS).
// else:   src is f16  [b][p][c] (contiguous tile copy, no transpose).
// EPI 0: relu(+bias|+u), store f16 [p][co] + GN stats
// EPI 1: +bias raw, store f16 hf4 [co][p] + GN stats
// EPI 2: +bias, mask(count), softmax(K) in regs, fused final:
//        out[b][co][n] = sum_k relu(s3*y3+t3)*softmax
template<int CIN, int COUT, bool SRCF32, int EPI, bool HASU,
         int WCOFF, int COOFF, bool WPB, bool BPB>
__global__ void __launch_bounds__(256, 2) gemm_k(
    const void* __restrict__ srcv, const _Float16* __restrict__ W,
    const float* __restrict__ bias, _Float16* __restrict__ outh,
    float* __restrict__ outf, float* __restrict__ stats,
    const float* __restrict__ u, const int* __restrict__ cnt,
    const _Float16* __restrict__ y3, const float* __restrict__ s3,
    const float* __restrict__ t3)
{
    constexpr int KC    = CIN / 32;
    constexpr int NT    = COUT / 64;
    constexpr int TILES = NK_ / 64;
    constexpr int LROW  = CIN + 4;

    __shared__ _Float16 xs[2][64][LROW];
    __shared__ float bstat[(EPI < 2) ? COUT * 2 : 1];

    const int tid  = threadIdx.x;
    const int lane = tid & 63;
    const int wave = tid >> 6;
    const int l15  = lane & 15;
    const int q    = lane >> 4;
    const int b    = blockIdx.y;
    const int tp   = tid & 15;   // SRCF32: position quad
    const int cq   = tid >> 4;   // SRCF32: channel group

    // persistent W fragments (B operand)
    hf8 bf[NT][KC];
    const _Float16* Wb = W + (WPB ? (size_t)b * COUT * 128 : 0);
    float biasr[NT], s3r[NT], t3r[NT];
    #pragma unroll
    for (int nt = 0; nt < NT; nt++) {
        int co = wave * 16 * NT + nt * 16 + l15;
        #pragma unroll
        for (int kc = 0; kc < KC; kc++)
            bf[nt][kc] = *(const hf8*)(Wb + (size_t)co * 128 + WCOFF + kc * 32 + q * 8);
        biasr[nt] = bias ? bias[(BPB ? b * COUT : 0) + co] : 0.0f;
        if (EPI == 2) { s3r[nt] = s3[b * 128 + co]; t3r[nt] = t3[b * 128 + co]; }
        else          { s3r[nt] = 0.0f; t3r[nt] = 0.0f; }
    }
    if (EPI < 2) for (int i = tid; i < COUT * 2; i += 256) bstat[i] = 0.0f;

    f4  pf [SRCF32 ? CIN / 64 : 1][4];
    hf8 pfh[SRCF32 ? 1 : CIN / 32];

    auto prefetch = [&](int t) {
        if constexpr (SRCF32) {
            const float* s = (const float*)srcv;
            int pbase = t * 64;
            #pragma unroll
            for (int ps = 0; ps < CIN / 64; ps++) {
                int c0 = (ps * 16 + cq) * 4;
                #pragma unroll
                for (int r = 0; r < 4; r++)
                    pf[ps][r] = *(const f4*)(s + ((size_t)b * CIN + c0 + r) * NK_ + pbase + tp * 4);
            }
        } else {
            const _Float16* s = (const _Float16*)srcv + ((size_t)b * NK_ + (size_t)t * 64) * CIN;
            #pragma unroll
            for (int j = 0; j < CIN / 32; j++)
                pfh[j] = *(const hf8*)(s + (j * 256 + tid) * 8);
        }
    };
    auto write_lds = [&](int buf) {
        if constexpr (SRCF32) {
            #pragma unroll
            for (int ps = 0; ps < CIN / 64; ps++) {
                int c0 = (ps * 16 + cq) * 4;
                #pragma unroll
                for (int i = 0; i < 4; i++) {
                    hf4 w = { (_Float16)pf[ps][0][i], (_Float16)pf[ps][1][i],
                              (_Float16)pf[ps][2][i], (_Float16)pf[ps][3][i] };
                    *(hf4*)&xs[buf][tp * 4 + i][c0] = w;
                }
            }
        } else {
            #pragma unroll
            for (int j = 0; j < CIN / 32; j++) {
                int idx = j * 256 + tid;
                int p = idx / (CIN / 8), c0 = (idx % (CIN / 8)) * 8;
                *(hf4*)&xs[buf][p][c0]     = __builtin_shufflevector(pfh[j], pfh[j], 0, 1, 2, 3);
                *(hf4*)&xs[buf][p][c0 + 4] = __builtin_shufflevector(pfh[j], pfh[j], 4, 5, 6, 7);
            }
        }
    };

    int buf = 0;
    int t0 = blockIdx.x;
    if (t0 < TILES) prefetch(t0);
    for (int t = t0; t < TILES; t += gridDim.x) {
        write_lds(buf);                 // waits the in-flight loads for tile t
        __syncthreads();
        int tn = t + (int)gridDim.x;
        if (tn < TILES) prefetch(tn);   // issued post-barrier: stays in flight
        const int pbase = t * 64, n0 = t * 2;

        float uv[2][NT]; int cv[2]; hf4 yf[4][NT];
        if constexpr (HASU) {
            #pragma unroll
            for (int pair = 0; pair < 2; pair++)
                #pragma unroll
                for (int nt = 0; nt < NT; nt++) {
                    int co = wave * 16 * NT + nt * 16 + l15;
                    uv[pair][nt] = u[((size_t)b * N_ + n0 + pair) * C_ + co];
                }
        }
        if constexpr (EPI == 2) {
            #pragma unroll
            for (int pair = 0; pair < 2; pair++) {
                int c = cnt[b * N_ + n0 + pair];
                cv[pair] = c < 1 ? 1 : c;
            }
            #pragma unroll
            for (int mt = 0; mt < 4; mt++)
                #pragma unroll
                for (int nt = 0; nt < NT; nt++) {
                    int co = wave * 16 * NT + nt * 16 + l15;
                    yf[mt][nt] = *(const hf4*)(y3 + ((size_t)b * 128 + co) * NK_ + pbase + mt * 16 + q * 4);
                }
        }

        f4 acc[4][NT];
        #pragma unroll
        for (int mt = 0; mt < 4; mt++)
            #pragma unroll
            for (int nt = 0; nt < NT; nt++) acc[mt][nt] = f4{0, 0, 0, 0};

        #pragma unroll
        for (int kc = 0; kc < KC; kc++) {
            hf8 af[4];
            #pragma unroll
            for (int mt = 0; mt < 4; mt++) {
                hf4 lo = *(const hf4*)&xs[buf][mt * 16 + l15][kc * 32 + q * 8];
                hf4 hi = *(const hf4*)&xs[buf][mt * 16 + l15][kc * 32 + q * 8 + 4];
                af[mt] = __builtin_shufflevector(lo, hi, 0, 1, 2, 3, 4, 5, 6, 7);
            }
            #pragma unroll
            for (int mt = 0; mt < 4; mt++)
                #pragma unroll
                for (int nt = 0; nt < NT; nt++)
                    acc[mt][nt] = __builtin_amdgcn_mfma_f32_16x16x32_f16(
                        af[mt], bf[nt][kc], acc[mt][nt], 0, 0, 0);
        }

        if constexpr (EPI == 0) {
            #pragma unroll
            for (int nt = 0; nt < NT; nt++) {
                int co = wave * 16 * NT + nt * 16 + l15;
                float s1 = 0.0f, s2 = 0.0f;
                #pragma unroll
                for (int mt = 0; mt < 4; mt++) {
                    float add = HASU ? uv[mt >> 1][nt] : biasr[nt];
                    #pragma unroll
                    for (int r = 0; r < 4; r++) {
                        float v = fmaxf(acc[mt][nt][r] + add, 0.0f);
                        s1 += v; s2 += v * v;
                        outh[((size_t)b * NK_ + pbase + mt * 16 + q * 4 + r) * COUT + co] = (_Float16)v;
                    }
                }
                s1 += __shfl_xor(s1, 16); s1 += __shfl_xor(s1, 32);
                s2 += __shfl_xor(s2, 16); s2 += __shfl_xor(s2, 32);
                if (q == 0) {
                    atomicAdd(&bstat[co * 2 + 0], s1);
                    atomicAdd(&bstat[co * 2 + 1], s2);
                }
            }
        } else if constexpr (EPI == 1) {
            #pragma unroll
            for (int nt = 0; nt < NT; nt++) {
                int co = wave * 16 * NT + nt * 16 + l15;
                float s1 = 0.0f, s2 = 0.0f;
                #pragma unroll
                for (int mt = 0; mt < 4; mt++) {
                    hf4 hv;
                    #pragma unroll
                    for (int r = 0; r < 4; r++) {
                        float v = acc[mt][nt][r] + biasr[nt];
                        s1 += v; s2 += v * v;
                        hv[r] = (_Float16)v;
                    }
                    *(hf4*)(outh + ((size_t)b * COUT + co) * NK_ + pbase + mt * 16 + q * 4) = hv;
                }
                s1 += __shfl_xor(s1, 16); s1 += __shfl_xor(s1, 32);
                s2 += __shfl_xor(s2, 16); s2 += __shfl_xor(s2, 32);
                if (q == 0) {
                    atomicAdd(&bstat[co * 2 + 0], s1);
                    atomicAdd(&bstat[co * 2 + 1], s2);
                }
            }
        } else {
            // scores -> mask -> softmax (fp32, regs) -> fused weighted sum
            #pragma unroll
            for (int nt = 0; nt < NT; nt++) {
                int co = wave * 16 * NT + nt * 16 + l15;
                float mx[2] = {-3e38f, -3e38f};
                #pragma unroll
                for (int mt = 0; mt < 4; mt++) {
                    int pair = mt >> 1, kb = (mt & 1) * 16;
                    #pragma unroll
                    for (int r = 0; r < 4; r++) {
                        float v = acc[mt][nt][r] + biasr[nt];
                        if (kb + q * 4 + r >= cv[pair]) v = -1e9f;
                        acc[mt][nt][r] = v;
                        mx[pair] = fmaxf(mx[pair], v);
                    }
                }
                mx[0] = fmaxf(mx[0], __shfl_xor(mx[0], 16)); mx[0] = fmaxf(mx[0], __shfl_xor(mx[0], 32));
                mx[1] = fmaxf(mx[1], __shfl_xor(mx[1], 16)); mx[1] = fmaxf(mx[1], __shfl_xor(mx[1], 32));
                float sm[2] = {0.0f, 0.0f};
                #pragma unroll
                for (int mt = 0; mt < 4; mt++) {
                    int pair = mt >> 1;
                    #pragma unroll
                    for (int r = 0; r < 4; r++) {
                        float e = __expf(acc[mt][nt][r] - mx[pair]);
                        acc[mt][nt][r] = e;
                        sm[pair] += e;
                    }
                }
                sm[0] += __shfl_xor(sm[0], 16); sm[0] += __shfl_xor(sm[0], 32);
                sm[1] += __shfl_xor(sm[1], 16); sm[1] += __shfl_xor(sm[1], 32);
                float os[2] = {0.0f, 0.0f};
                #pragma unroll
                for (int mt = 0; mt < 4; mt++) {
                    int pair = mt >> 1;
                    #pragma unroll
                    for (int r = 0; r < 4; r++) {
                        float g = fmaxf(s3r[nt] * (float)yf[mt][nt][r] + t3r[nt], 0.0f);
                        os[pair] += g * acc[mt][nt][r];
                    }
                }
                os[0] += __shfl_xor(os[0], 16); os[0] += __shfl_xor(os[0], 32);
                os[1] += __shfl_xor(os[1], 16); os[1] += __shfl_xor(os[1], 32);
                if (q == 0) {
                    outf[((size_t)b * 128 + co) * N_ + n0 + 0] = os[0] / sm[0];
                    outf[((size_t)b * 128 + co) * N_ + n0 + 1] = os[1] / sm[1];
                }
            }
        }
        buf ^= 1;
    }

    if constexpr (EPI < 2) {
        __syncthreads();
        for (int i = tid; i < COUT * 2; i += 256) {
            int co = i >> 1, j = i & 1;
            int g = (co + COOFF) >> 2;
            atomicAdd(&stats[(b * 32 + g) * 2 + j], bstat[i]);
        }
    }
}

// ---------------------------------------------------------------------------
extern "C" void kernel_launch(void* const* d_in, const int* in_sizes, int n_in,
                              void* d_out, int out_size, void* d_ws, size_t ws_size,
                              hipStream_t stream)
{
    (void)in_sizes; (void)n_in; (void)out_size; (void)ws_size;
    const float* feat   = (const float*)d_in[0];
    const float* gf     = (const float*)d_in[1];
    const float* gfo    = (const float*)d_in[2];
    const int*   count  = (const int*)d_in[3];
    const float* W_feat = (const float*)d_in[4];
    const float* b_feat = (const float*)d_in[5];
    const float* W_grp  = (const float*)d_in[6];
    const float* b_grp  = (const float*)d_in[7];
    const float* gn1w   = (const float*)d_in[8];
    const float* gn1b   = (const float*)d_in[9];
    const float* W_wc1  = (const float*)d_in[10];
    const float* b_wc1  = (const float*)d_in[11];
    const float* gn2w   = (const float*)d_in[12];
    const float* gn2b   = (const float*)d_in[13];
    const float* W_wc2  = (const float*)d_in[14];
    const float* b_wc2  = (const float*)d_in[15];
    const float* W_fo   = (const float*)d_in[16];
    const float* b_fo   = (const float*)d_in[17];
    const float* gn3w   = (const float*)d_in[18];
    const float* gn3b   = (const float*)d_in[19];
    float* out = (float*)d_out;

    char* ws = (char*)d_ws;
    size_t o = 0;
    auto alloc = [&](size_t bytes) { size_t r = o; o += (bytes + 255) & ~(size_t)255; return r; };
    _Float16* x1h    = (_Float16*)(ws + alloc((size_t)64 * B_ * NK_ * 2));   // [b][p][64]
    _Float16* x2     = (_Float16*)(ws + alloc((size_t)128 * B_ * NK_ * 2));  // [b][p][128]
    _Float16* y3     = (_Float16*)(ws + alloc((size_t)128 * B_ * NK_ * 2));  // [b][co][p]
    float*    f1r    = (float*)(ws + alloc((size_t)B_ * 64 * N_ * 4));
    float*    u      = (float*)(ws + alloc((size_t)B_ * N_ * 128 * 4));
    float*    stats1 = (float*)(ws + alloc(256 * 4));
    float*    stats2 = (float*)(ws + alloc(256 * 4));
    float*    stats3 = (float*)(ws + alloc(256 * 4));
    _Float16* Wgrp_h = (_Float16*)(ws + alloc(64 * 128 * 2));
    _Float16* Wfo_h  = (_Float16*)(ws + alloc(128 * 128 * 2));
    _Float16* W1p    = (_Float16*)(ws + alloc((size_t)B_ * 128 * 128 * 2));
    float*    b1p    = (float*)(ws + alloc(B_ * 128 * 4));
    _Float16* W2p    = (_Float16*)(ws + alloc((size_t)B_ * 128 * 128 * 2));
    float*    b2p    = (float*)(ws + alloc(B_ * 128 * 4));
    float*    s3     = (float*)(ws + alloc(B_ * 128 * 4));
    float*    t3     = (float*)(ws + alloc(B_ * 128 * 4));

    prep_k<<<64, 256, 0, stream>>>(W_grp, W_fo, Wgrp_h, Wfo_h, stats1);
    feat_k<<<dim3(64, B_), 256, 0, stream>>>(feat, W_feat, b_feat, f1r, stats1);
    // K2: x1h = relu(W_grp @ gf + b_grp), stats -> gn1 groups 16..31
    gemm_k<128, 64, true, 0, false, 0, 64, false, false>
        <<<dim3(512, B_), 256, 0, stream>>>(gf, Wgrp_h, b_grp, x1h, nullptr, stats1,
                                            nullptr, nullptr, nullptr, nullptr, nullptr);
    fold_k<<<B_, 256, 0, stream>>>(stats1, gn1w, gn1b, W_wc1, b_wc1, W1p, b1p, nullptr, nullptr, 1);
    upass_k<<<dim3(128, B_), 256, 0, stream>>>(f1r, W1p, b1p, u);
    // K6: x2 = relu(W1p_hi @ x1h + u), stats -> gn2
    gemm_k<64, 128, false, 0, true, 64, 0, true, false>
        <<<dim3(512, B_), 256, 0, stream>>>(x1h, W1p, nullptr, x2, nullptr, stats2,
                                            u, nullptr, nullptr, nullptr, nullptr);
    // K3: y3 = W_fo @ gfo + b_fo (raw), stats -> gn3
    gemm_k<128, 128, true, 1, false, 0, 0, false, false>
        <<<dim3(512, B_), 256, 0, stream>>>(gfo, Wfo_h, b_fo, y3, nullptr, stats3,
                                            nullptr, nullptr, nullptr, nullptr, nullptr);
    fold_k<<<B_, 256, 0, stream>>>(stats2, gn2w, gn2b, W_wc2, b_wc2, W2p, b2p, nullptr, nullptr, 0);
    fold_k<<<B_, 256, 0, stream>>>(stats3, gn3w, gn3b, nullptr, nullptr, nullptr, nullptr, s3, t3, 0);
    // K8: scores -> softmax -> fused weighted sum -> out
    gemm_k<128, 128, false, 2, false, 0, 0, true, true>
        <<<dim3(512, B_), 256, 0, stream>>>(x2, W2p, b2p, nullptr, out, nullptr,
                                            nullptr, count, y3, s3, t3);
}